// Round 5
// baseline (245.524 us; speedup 1.0000x reference)
//
#include <hip/hip_runtime.h>
#include <cstdint>

// Problem constants
#define LN_EPS 1e-5f

typedef _Float16 f16;
typedef _Float16 half4_t __attribute__((ext_vector_type(4)));
typedef _Float16 half8_t __attribute__((ext_vector_type(8)));
typedef __fp16 fp16v2 __attribute__((ext_vector_type(2)));
typedef float f32x4 __attribute__((ext_vector_type(4)));

// async global->LDS, 16B per lane; LDS dest = wave-uniform base + lane*16
__device__ __forceinline__ void gl_lds16(const void* g, void* l) {
    __builtin_amdgcn_global_load_lds(
        (__attribute__((address_space(1))) void*)(uintptr_t)g,
        (__attribute__((address_space(3))) void*)(uint32_t)(uintptr_t)l,
        16, 0, 0);
}

// pack 4 floats -> 4 f16 via v_cvt_pkrtz
__device__ __forceinline__ half4_t pack4(float a, float b, float c, float d) {
    fp16v2 lo = __builtin_amdgcn_cvt_pkrtz(a, b);
    fp16v2 hi = __builtin_amdgcn_cvt_pkrtz(c, d);
    half4_t r;
    r[0] = (f16)lo[0]; r[1] = (f16)lo[1]; r[2] = (f16)hi[0]; r[3] = (f16)hi[1];
    return r;
}

// ---------------------------------------------------------------- cast weights
__global__ void k_cast(const float* __restrict__ W1f, const float* __restrict__ W2f,
                       f16* __restrict__ W1h, f16* __restrict__ W2h) {
    int t = blockIdx.x * blockDim.x + threadIdx.x;   // 262144 threads
    const int n1 = (1536 * 512) / 4;                 // 196608 float4 of W1
    const float4* src;
    half4_t* dst;
    int idx;
    if (t < n1) { src = (const float4*)W1f; dst = (half4_t*)W1h; idx = t; }
    else        { src = (const float4*)W2f; dst = (half4_t*)W2h; idx = t - n1; }
    float4 v = src[idx];
    dst[idx] = pack4(v.x, v.y, v.z, v.w);
}

// ---------------------------------------------------------------- in-projection
// C = X @ W^T + b ; outputs in chunk-major per-(n,h) layout: T[g][c][len][8],
// g=n*16+h, c=d-chunk (d = c*8+e). Q additionally pre-scaled by beta*log2(e).
// MFMA operands SWAPPED: C m-dim = feature (regs), n-dim = X row (lanes) ->
// epilogue packs 4 consecutive features per reg group (b64 stores).
__global__ __launch_bounds__(256) void k_inproj(
    const float* __restrict__ Xq, const float* __restrict__ Xk, const float* __restrict__ Xv,
    const f16* __restrict__ W1, const float* __restrict__ bias,
    const float* __restrict__ scaling,
    f16* __restrict__ Qg, f16* __restrict__ Kg, f16* __restrict__ Vg)
{
    __shared__ __align__(16) f16 Al[128 * 32];
    __shared__ __align__(16) f16 Bl[128 * 32];

    const int tid = threadIdx.x;
    const int m0 = blockIdx.x * 128;
    const int f0 = blockIdx.y * 128;          // global output-feature base [0,1536)
    const int sec = f0 >> 9;
    const float* X = (sec == 0) ? Xq : ((sec == 1) ? Xk : Xv);
    f16* Ob = (sec == 0) ? Qg : ((sec == 1) ? Kg : Vg);
    const int fl0 = f0 & 511;

    const int wid = tid >> 6, ln = tid & 63, l15 = ln & 15, quad = ln >> 4;
    const int wm = wid >> 1, wn = wid & 1;

    f32x4 z4 = {0.f, 0.f, 0.f, 0.f};
    f32x4 acc[4][4];
    #pragma unroll
    for (int i = 0; i < 4; ++i)
        #pragma unroll
        for (int j = 0; j < 4; ++j) acc[i][j] = z4;

    for (int kt = 0; kt < 16; ++kt) {
        const int k0 = kt * 32;
        #pragma unroll
        for (int i = 0; i < 2; ++i) {
            int row = wid * 32 + i * 16 + (ln >> 2);
            gl_lds16(W1 + (size_t)(f0 + row) * 512 + k0 + (ln & 3) * 8,
                     Bl + (wid * 32 + i * 16) * 32);
        }
        #pragma unroll
        for (int c = 0; c < 4; ++c) {
            int ch = c * 256 + tid;          // 0..1023 chunks of 4 floats
            int row = ch >> 3, q4 = ch & 7;
            float4 v = *(const float4*)(X + (size_t)(m0 + row) * 512 + k0 + q4 * 4);
            *(half4_t*)(Al + row * 32 + q4 * 4) = pack4(v.x, v.y, v.z, v.w);
        }
        __syncthreads();

        half8_t a[4], b[4];
        #pragma unroll
        for (int i = 0; i < 4; ++i)
            a[i] = *(const half8_t*)(Al + (wm * 64 + i * 16 + l15) * 32 + quad * 8);
        #pragma unroll
        for (int j = 0; j < 4; ++j)
            b[j] = *(const half8_t*)(Bl + (wn * 64 + j * 16 + l15) * 32 + quad * 8);
        #pragma unroll
        for (int i = 0; i < 4; ++i)
            #pragma unroll
            for (int j = 0; j < 4; ++j)
                acc[i][j] = __builtin_amdgcn_mfma_f32_16x16x32_f16(b[j], a[i], acc[i][j], 0, 0, 0);
        __syncthreads();
    }

    // epilogue: C cols (l15) = X row, C rows (quad*4+r) = feature.
    #pragma unroll
    for (int j = 0; j < 4; ++j) {
        int fb = f0 + wn * 64 + j * 16;       // feature base of this 16-tile
        int floc = (fb & 511) + quad * 4;     // per-lane feature within section
        int hh = floc >> 5;
        int cc = (floc >> 3) & 3, e0 = floc & 7;
        float sc2 = (sec == 0) ? scaling[hh] * 1.44269504f : 1.0f;
        float4 bs4 = *(const float4*)(bias + fb + quad * 4);
        #pragma unroll
        for (int i = 0; i < 4; ++i) {
            int rm = m0 + wm * 64 + i * 16 + l15;
            int l = rm >> 2, nb = rm & 3;
            int gg = nb * 16 + hh;
            *(half4_t*)(Ob + (size_t)gg * 65536 + (size_t)cc * 16384 + (size_t)l * 8 + e0) =
                pack4((acc[i][j][0] + bs4.x) * sc2, (acc[i][j][1] + bs4.y) * sc2,
                      (acc[i][j][2] + bs4.z) * sc2, (acc[i][j][3] + bs4.w) * sc2);
        }
    }
}

// ---------------------------------------------------------------- LayerNorm on K (in place)
// Kg layout [g][c][2048][8]; one thread per (g,s): in-thread LN over 32 d.
__global__ void k_norm_k(f16* __restrict__ Kg, const float* __restrict__ w,
                         const float* __restrict__ b) {
    int t = blockIdx.x * 256 + threadIdx.x;   // 131072
    int g = t >> 11, s = t & 2047;
    f16* base = Kg + (size_t)g * 65536 + (size_t)s * 8;
    half8_t x[4];
    float xf[32], s1 = 0.f, s2 = 0.f;
    #pragma unroll
    for (int c = 0; c < 4; ++c) {
        x[c] = *(const half8_t*)(base + (size_t)c * 16384);
        #pragma unroll
        for (int j = 0; j < 8; ++j) {
            float v = (float)x[c][j];
            xf[c * 8 + j] = v; s1 += v; s2 += v * v;
        }
    }
    float mean = s1 * (1.f / 32.f);
    float var = s2 * (1.f / 32.f) - mean * mean;
    float rs = rsqrtf(var + LN_EPS);
    #pragma unroll
    for (int c = 0; c < 4; ++c) {
        half8_t y;
        #pragma unroll
        for (int j = 0; j < 8; ++j) {
            int d = c * 8 + j;
            y[j] = (f16)((xf[d] - mean) * rs * w[d] + b[d]);
        }
        *(half8_t*)(base + (size_t)c * 16384) = y;
    }
}

// ---------------------------------------------------------------- LayerNorm + transpose on V
// Vg [g][c][2048][8] -> Vtg [g][seg][d=32][c'=8][8] with c' = c_s XOR (d&7)
__global__ void k_norm_vt(const f16* __restrict__ Vg, const float* __restrict__ w,
                          const float* __restrict__ b, f16* __restrict__ Vtg) {
    __shared__ __align__(16) f16 T[32 * 64];   // [d][c'][8]
    const int t = threadIdx.x;
    const int seg = blockIdx.x, g = blockIdx.y;
    const int s_l = t >> 2, c = t & 3;
    half8_t v = *(const half8_t*)(Vg + (size_t)g * 65536 + (size_t)c * 16384 +
                                  (size_t)(seg * 64 + s_l) * 8);
    float xf[8], s1 = 0.f, s2 = 0.f;
    #pragma unroll
    for (int j = 0; j < 8; ++j) { xf[j] = (float)v[j]; s1 += xf[j]; s2 += xf[j] * xf[j]; }
    s1 += __shfl_xor(s1, 1); s1 += __shfl_xor(s1, 2);
    s2 += __shfl_xor(s2, 1); s2 += __shfl_xor(s2, 2);
    float mean = s1 * (1.f / 32.f);
    float var = s2 * (1.f / 32.f) - mean * mean;
    float rs = rsqrtf(var + LN_EPS);
    int cs = s_l >> 3, es = s_l & 7;
    #pragma unroll
    for (int j = 0; j < 8; ++j) {
        int d = c * 8 + j;
        T[d * 64 + (cs ^ j) * 8 + es] = (f16)((xf[j] - mean) * rs * w[d] + b[d]);
    }
    __syncthreads();
    int d_o = t >> 3, c_o = t & 7;
    half8_t out = *(const half8_t*)(T + d_o * 64 + c_o * 8);
    *(half8_t*)(Vtg + (size_t)(g * 32 + seg) * 2048 + d_o * 64 + c_o * 8) = out;
}

// ---------------------------------------------------------------- flash attention
// Q-tile 64, 4 waves (wave owns 16 q), S-tile 64, double-buffered K/V staging.
// Bottom-barrier pipeline: prefetch st+1 -> compute st -> EXPLICIT vmcnt(0) drain
// -> barrier. The explicit s_waitcnt guards against the compiler failing to
// carry pending LDS-DMA state across the loop back-edge (R4 replay race).
__global__ __launch_bounds__(256, 6) void k_flash(
    const f16* __restrict__ Qg, const f16* __restrict__ Kg,
    const f16* __restrict__ Vtg, f16* __restrict__ Og)
{
    __shared__ __align__(16) char smem[25600];
    // Kb[2]: 0 / 4096 ; Vb[2]: 8192 / 12288 ; P: 16384 + wid*2304 (Q staged there too)

    const int tid = threadIdx.x, wid = tid >> 6, ln = tid & 63;
    const int l15 = ln & 15, quad = ln >> 4;
    char* Pw = smem + 16384 + wid * 2304;
    const int g = blockIdx.y, h = g & 15, n = g >> 4;
    const int q0 = blockIdx.x * 64;

    // prologue: stage Q (into P region), K0, V0 into buffer 0
    gl_lds16(Qg + (size_t)g * 65536 + (size_t)wid * 16384 + (size_t)(q0 + ln) * 8,
             smem + 16384 + wid * 1024);
    gl_lds16(Kg + (size_t)g * 65536 + (size_t)wid * 16384 + (size_t)ln * 8,
             smem + wid * 1024);
    gl_lds16(Vtg + (size_t)(g * 32 + 0) * 2048 + wid * 512 + ln * 8,
             smem + 8192 + wid * 1024);
    __builtin_amdgcn_s_waitcnt(0x0F70);   // vmcnt(0), explicit
    __syncthreads();
    half8_t aq = *(const half8_t*)(smem + 16384 + quad * 1024 + (wid * 16 + l15) * 16);

    f32x4 z4 = {0.f, 0.f, 0.f, 0.f};
    f32x4 accO[2];
    accO[0] = z4; accO[1] = z4;
    float m_i = -1e30f, l_i = 0.f;

    for (int st = 0; st < 32; ++st) {
        const int cur = st & 1, nxt = cur ^ 1;
        // prefetch tile st+1 (buffer nxt was last read at st-1, separated by barrier)
        if (st < 31) {
            gl_lds16(Kg + (size_t)g * 65536 + (size_t)wid * 16384 + (size_t)((st + 1) * 64 + ln) * 8,
                     smem + nxt * 4096 + wid * 1024);
            gl_lds16(Vtg + (size_t)(g * 32 + st + 1) * 2048 + wid * 512 + ln * 8,
                     smem + 8192 + nxt * 4096 + wid * 1024);
        }
        const char* Kl = smem + cur * 4096;
        const char* Vt = smem + 8192 + cur * 4096;

        // S^T tile: A = K (m=s), B = Qscaled (n=q); already in exp2 units
        half8_t ak[4];
        #pragma unroll
        for (int mt = 0; mt < 4; ++mt)
            ak[mt] = *(const half8_t*)(Kl + quad * 1024 + (mt * 16 + l15) * 16);
        f32x4 accS[4];
        #pragma unroll
        for (int mt = 0; mt < 4; ++mt)
            accS[mt] = __builtin_amdgcn_mfma_f32_16x16x32_f16(ak[mt], aq, z4, 0, 0, 0);

        // online softmax per q (= lane col l15); cross-lane reduce over quads
        float xmax = accS[0][0];
        #pragma unroll
        for (int mt = 0; mt < 4; ++mt)
            #pragma unroll
            for (int r = 0; r < 4; ++r) xmax = fmaxf(xmax, accS[mt][r]);
        xmax = fmaxf(xmax, __shfl_xor(xmax, 16));
        xmax = fmaxf(xmax, __shfl_xor(xmax, 32));
        float mnew = fmaxf(m_i, xmax);
        float alpha = __builtin_amdgcn_exp2f(m_i - mnew);
        float rs = 0.f;
        #pragma unroll
        for (int mt = 0; mt < 4; ++mt) {
            float p0 = __builtin_amdgcn_exp2f(accS[mt][0] - mnew);
            float p1 = __builtin_amdgcn_exp2f(accS[mt][1] - mnew);
            float p2 = __builtin_amdgcn_exp2f(accS[mt][2] - mnew);
            float p3 = __builtin_amdgcn_exp2f(accS[mt][3] - mnew);
            rs += (p0 + p1) + (p2 + p3);
            *(half4_t*)(Pw + l15 * 144 + mt * 32 + quad * 8) = pack4(p0, p1, p2, p3);
        }
        rs += __shfl_xor(rs, 16);
        rs += __shfl_xor(rs, 32);
        l_i = l_i * alpha + rs;
        m_i = mnew;
        #pragma unroll
        for (int dt = 0; dt < 2; ++dt)
            #pragma unroll
            for (int r = 0; r < 4; ++r) accO[dt][r] *= alpha;

        // O^T += V^T · P^T : A = V^T (m=d), B = P^T (n=q); P is wave-private
        #pragma unroll
        for (int kt = 0; kt < 2; ++kt) {
            half8_t av[2], bp;
            #pragma unroll
            for (int dt = 0; dt < 2; ++dt) {
                int d = dt * 16 + l15;
                int cp = (kt * 4 + quad) ^ (l15 & 7);
                av[dt] = *(const half8_t*)(Vt + d * 128 + cp * 16);
            }
            bp = *(const half8_t*)(Pw + l15 * 144 + kt * 64 + quad * 16);
            #pragma unroll
            for (int dt = 0; dt < 2; ++dt)
                accO[dt] = __builtin_amdgcn_mfma_f32_16x16x32_f16(av[dt], bp, accO[dt], 0, 0, 0);
        }

        // drain prefetch DMA + everyone's reads of cur, then cross the tile boundary
        __builtin_amdgcn_s_waitcnt(0x0F70);   // vmcnt(0), explicit (R4 race fix)
        __syncthreads();
    }

    // epilogue: normalize; transpose via wave-private LDS (16 rows x 80 B stride);
    // write Og[n][l][512] coalesced. Loop ended with a barrier.
    float inv = 1.f / l_i;
    #pragma unroll
    for (int dt = 0; dt < 2; ++dt)
        *(half4_t*)(Pw + l15 * 80 + (dt * 16 + quad * 4) * 2) =
            pack4(accO[dt][0] * inv, accO[dt][1] * inv,
                  accO[dt][2] * inv, accO[dt][3] * inv);
    int q2 = ln >> 2, c4 = ln & 3;
    half8_t o = *(const half8_t*)(Pw + q2 * 80 + c4 * 16);
    *(half8_t*)(Og + ((size_t)(n * 2048 + q0 + wid * 16 + q2)) * 512 + h * 32 + c4 * 8) = o;
}

// ---------------------------------------------------------------- out-projection
// Out = O @ W2^T + b ; O f16 [n][l][512] (rows m = n*2048+l), Out f32 rows l*4+n.
// MFMA operands swapped: C rows = feature -> float4 stores, full-line coalescing.
__global__ __launch_bounds__(256) void k_outproj(
    const f16* __restrict__ A, const f16* __restrict__ W2,
    const float* __restrict__ bias, float* __restrict__ Out)
{
    __shared__ __align__(16) f16 Al[128 * 32];
    __shared__ __align__(16) f16 Bl[128 * 32];

    const int tid = threadIdx.x;
    const int m0 = blockIdx.x * 128;
    const int f0 = blockIdx.y * 128;
    const int wid = tid >> 6, ln = tid & 63, l15 = ln & 15, quad = ln >> 4;
    const int wm = wid >> 1, wn = wid & 1;

    f32x4 z4 = {0.f, 0.f, 0.f, 0.f};
    f32x4 acc[4][4];
    #pragma unroll
    for (int i = 0; i < 4; ++i)
        #pragma unroll
        for (int j = 0; j < 4; ++j) acc[i][j] = z4;

    for (int kt = 0; kt < 16; ++kt) {
        const int k0 = kt * 32;
        #pragma unroll
        for (int i = 0; i < 2; ++i) {
            int row = wid * 32 + i * 16 + (ln >> 2);
            gl_lds16(A + (size_t)(m0 + row) * 512 + k0 + (ln & 3) * 8,
                     Al + (wid * 32 + i * 16) * 32);
            gl_lds16(W2 + (size_t)(f0 + row) * 512 + k0 + (ln & 3) * 8,
                     Bl + (wid * 32 + i * 16) * 32);
        }
        __syncthreads();

        half8_t a[4], b[4];
        #pragma unroll
        for (int i = 0; i < 4; ++i)
            a[i] = *(const half8_t*)(Al + (wm * 64 + i * 16 + l15) * 32 + quad * 8);
        #pragma unroll
        for (int j = 0; j < 4; ++j)
            b[j] = *(const half8_t*)(Bl + (wn * 64 + j * 16 + l15) * 32 + quad * 8);
        #pragma unroll
        for (int i = 0; i < 4; ++i)
            #pragma unroll
            for (int j = 0; j < 4; ++j)
                acc[i][j] = __builtin_amdgcn_mfma_f32_16x16x32_f16(b[j], a[i], acc[i][j], 0, 0, 0);
        __syncthreads();
    }

    // epilogue: C cols (l15) = A row, C rows (quad*4+r) = feature -> float4 store
    #pragma unroll
    for (int j = 0; j < 4; ++j) {
        int fb = f0 + wn * 64 + j * 16;
        float4 bs4 = *(const float4*)(bias + fb + quad * 4);
        #pragma unroll
        for (int i = 0; i < 4; ++i) {
            int rm = m0 + wm * 64 + i * 16 + l15;
            int orow = (rm & 2047) * 4 + (rm >> 11);
            float4 o;
            o.x = acc[i][j][0] + bs4.x;
            o.y = acc[i][j][1] + bs4.y;
            o.z = acc[i][j][2] + bs4.z;
            o.w = acc[i][j][3] + bs4.w;
            *(float4*)(Out + (size_t)orow * 512 + fb + quad * 4) = o;
        }
    }
}

// ---------------------------------------------------------------- launch
extern "C" void kernel_launch(void* const* d_in, const int* in_sizes, int n_in,
                              void* d_out, int out_size, void* d_ws, size_t ws_size,
                              hipStream_t stream) {
    const float* query   = (const float*)d_in[0];
    const float* key_in  = (const float*)d_in[1];
    const float* value   = (const float*)d_in[2];
    const float* scaling = (const float*)d_in[3];
    const float* ipw     = (const float*)d_in[4];
    const float* ipb     = (const float*)d_in[5];
    const float* pnw     = (const float*)d_in[6];
    const float* pnb     = (const float*)d_in[7];
    const float* opw     = (const float*)d_in[8];
    const float* opb     = (const float*)d_in[9];
    float* out = (float*)d_out;

    // workspace (f16 elements): Qg,Kg,Vg,Vtg each 4,194,304; W1 786,432; W2 262,144
    // Og aliases Vg (Vg fully consumed by k_norm_vt before k_flash writes Og).
    f16* Qg  = (f16*)d_ws;
    f16* Kg  = Qg  + (size_t)4194304;
    f16* Vg  = Kg  + (size_t)4194304;
    f16* Vtg = Vg  + (size_t)4194304;
    f16* W1  = Vtg + (size_t)4194304;
    f16* W2  = W1  + (size_t)786432;
    f16* Og  = Vg;   // alias
    // total: 35,651,584 bytes

    k_cast<<<1024, 256, 0, stream>>>(ipw, opw, W1, W2);
    k_inproj<<<dim3(64, 12), 256, 0, stream>>>(query, key_in, value, W1, ipb, scaling, Qg, Kg, Vg);
    k_norm_k<<<512, 256, 0, stream>>>(Kg, pnw, pnb);
    k_norm_vt<<<dim3(32, 64), 256, 0, stream>>>(Vg, pnw, pnb, Vtg);
    k_flash<<<dim3(32, 64), 256, 0, stream>>>(Qg, Kg, Vtg, Og);
    k_outproj<<<dim3(64, 4), 256, 0, stream>>>(Og, W2, opb, out);
}

// Round 6
// 230.993 us; speedup vs baseline: 1.0629x; 1.0629x over previous
//
#include <hip/hip_runtime.h>
#include <cstdint>

// Problem constants
#define LN_EPS 1e-5f

typedef _Float16 f16;
typedef _Float16 half4_t __attribute__((ext_vector_type(4)));
typedef _Float16 half8_t __attribute__((ext_vector_type(8)));
typedef __fp16 fp16v2 __attribute__((ext_vector_type(2)));
typedef float f32x4 __attribute__((ext_vector_type(4)));

// async global->LDS, 16B per lane; LDS dest = wave-uniform base + lane*16
__device__ __forceinline__ void gl_lds16(const void* g, void* l) {
    __builtin_amdgcn_global_load_lds(
        (__attribute__((address_space(1))) void*)(uintptr_t)g,
        (__attribute__((address_space(3))) void*)(uint32_t)(uintptr_t)l,
        16, 0, 0);
}

// pack 4 floats -> 4 f16 via v_cvt_pkrtz
__device__ __forceinline__ half4_t pack4(float a, float b, float c, float d) {
    fp16v2 lo = __builtin_amdgcn_cvt_pkrtz(a, b);
    fp16v2 hi = __builtin_amdgcn_cvt_pkrtz(c, d);
    half4_t r;
    r[0] = (f16)lo[0]; r[1] = (f16)lo[1]; r[2] = (f16)hi[0]; r[3] = (f16)hi[1];
    return r;
}

// ---------------------------------------------------------------- cast weights
__global__ void k_cast(const float* __restrict__ W1f, const float* __restrict__ W2f,
                       f16* __restrict__ W1h, f16* __restrict__ W2h) {
    int t = blockIdx.x * blockDim.x + threadIdx.x;   // 262144 threads
    const int n1 = (1536 * 512) / 4;                 // 196608 float4 of W1
    const float4* src;
    half4_t* dst;
    int idx;
    if (t < n1) { src = (const float4*)W1f; dst = (half4_t*)W1h; idx = t; }
    else        { src = (const float4*)W2f; dst = (half4_t*)W2h; idx = t - n1; }
    float4 v = src[idx];
    dst[idx] = pack4(v.x, v.y, v.z, v.w);
}

// ---------------------------------------------------------------- in-projection
// C = X @ W^T + b ; outputs in chunk-major per-(n,h) layout: T[g][c][len][8],
// g=n*16+h, c=d-chunk (d = c*8+e). Q additionally pre-scaled by beta*log2(e).
__global__ __launch_bounds__(256) void k_inproj(
    const float* __restrict__ Xq, const float* __restrict__ Xk, const float* __restrict__ Xv,
    const f16* __restrict__ W1, const float* __restrict__ bias,
    const float* __restrict__ scaling,
    f16* __restrict__ Qg, f16* __restrict__ Kg, f16* __restrict__ Vg)
{
    __shared__ __align__(16) f16 Al[128 * 32];
    __shared__ __align__(16) f16 Bl[128 * 32];

    const int tid = threadIdx.x;
    const int m0 = blockIdx.x * 128;
    const int f0 = blockIdx.y * 128;          // global output-feature base [0,1536)
    const int sec = f0 >> 9;
    const float* X = (sec == 0) ? Xq : ((sec == 1) ? Xk : Xv);
    f16* Ob = (sec == 0) ? Qg : ((sec == 1) ? Kg : Vg);

    const int wid = tid >> 6, ln = tid & 63, l15 = ln & 15, quad = ln >> 4;
    const int wm = wid >> 1, wn = wid & 1;

    f32x4 z4 = {0.f, 0.f, 0.f, 0.f};
    f32x4 acc[4][4];
    #pragma unroll
    for (int i = 0; i < 4; ++i)
        #pragma unroll
        for (int j = 0; j < 4; ++j) acc[i][j] = z4;

    for (int kt = 0; kt < 16; ++kt) {
        const int k0 = kt * 32;
        #pragma unroll
        for (int i = 0; i < 2; ++i) {
            int row = wid * 32 + i * 16 + (ln >> 2);
            gl_lds16(W1 + (size_t)(f0 + row) * 512 + k0 + (ln & 3) * 8,
                     Bl + (wid * 32 + i * 16) * 32);
        }
        #pragma unroll
        for (int c = 0; c < 4; ++c) {
            int ch = c * 256 + tid;          // 0..1023 chunks of 4 floats
            int row = ch >> 3, q4 = ch & 7;
            float4 v = *(const float4*)(X + (size_t)(m0 + row) * 512 + k0 + q4 * 4);
            *(half4_t*)(Al + row * 32 + q4 * 4) = pack4(v.x, v.y, v.z, v.w);
        }
        __syncthreads();

        half8_t a[4], b[4];
        #pragma unroll
        for (int i = 0; i < 4; ++i)
            a[i] = *(const half8_t*)(Al + (wm * 64 + i * 16 + l15) * 32 + quad * 8);
        #pragma unroll
        for (int j = 0; j < 4; ++j)
            b[j] = *(const half8_t*)(Bl + (wn * 64 + j * 16 + l15) * 32 + quad * 8);
        #pragma unroll
        for (int i = 0; i < 4; ++i)
            #pragma unroll
            for (int j = 0; j < 4; ++j)
                acc[i][j] = __builtin_amdgcn_mfma_f32_16x16x32_f16(b[j], a[i], acc[i][j], 0, 0, 0);
        __syncthreads();
    }

    // epilogue: C cols (l15) = X row, C rows (quad*4+r) = feature.
    #pragma unroll
    for (int j = 0; j < 4; ++j) {
        int fb = f0 + wn * 64 + j * 16;       // feature base of this 16-tile
        int floc = (fb & 511) + quad * 4;     // per-lane feature within section
        int hh = floc >> 5;
        int cc = (floc >> 3) & 3, e0 = floc & 7;
        float sc2 = (sec == 0) ? scaling[hh] * 1.44269504f : 1.0f;
        float4 bs4 = *(const float4*)(bias + fb + quad * 4);
        #pragma unroll
        for (int i = 0; i < 4; ++i) {
            int rm = m0 + wm * 64 + i * 16 + l15;
            int l = rm >> 2, nb = rm & 3;
            int gg = nb * 16 + hh;
            *(half4_t*)(Ob + (size_t)gg * 65536 + (size_t)cc * 16384 + (size_t)l * 8 + e0) =
                pack4((acc[i][j][0] + bs4.x) * sc2, (acc[i][j][1] + bs4.y) * sc2,
                      (acc[i][j][2] + bs4.z) * sc2, (acc[i][j][3] + bs4.w) * sc2);
        }
    }
}

// ---------------------------------------------------------------- LayerNorm K (in place) + V (normed, transposed)
// grid (32, 64): seg=64 s-rows, g. thread (s_l = t>>2, c = t&3) per matrix.
// Vg [g][c][2048][8] -> Vtg [g][seg][d=32][c'=8][8], c' = c_s XOR (d&7)
__global__ void k_norm_kv(f16* __restrict__ Kg, const f16* __restrict__ Vg,
                          const float* __restrict__ w, const float* __restrict__ b,
                          f16* __restrict__ Vtg) {
    __shared__ __align__(16) f16 T[32 * 64];   // [d][c'][8]
    const int t = threadIdx.x;
    const int seg = blockIdx.x, g = blockIdx.y;
    const int s_l = t >> 2, c = t & 3;
    const size_t base = (size_t)g * 65536 + (size_t)c * 16384 + (size_t)(seg * 64 + s_l) * 8;

    half8_t kv = *(const half8_t*)(Kg + base);
    half8_t vv = *(const half8_t*)(Vg + base);
    float kf[8], vf[8];
    float ks1 = 0.f, ks2 = 0.f, vs1 = 0.f, vs2 = 0.f;
    #pragma unroll
    for (int j = 0; j < 8; ++j) {
        kf[j] = (float)kv[j]; ks1 += kf[j]; ks2 += kf[j] * kf[j];
        vf[j] = (float)vv[j]; vs1 += vf[j]; vs2 += vf[j] * vf[j];
    }
    ks1 += __shfl_xor(ks1, 1); ks1 += __shfl_xor(ks1, 2);
    ks2 += __shfl_xor(ks2, 1); ks2 += __shfl_xor(ks2, 2);
    vs1 += __shfl_xor(vs1, 1); vs1 += __shfl_xor(vs1, 2);
    vs2 += __shfl_xor(vs2, 1); vs2 += __shfl_xor(vs2, 2);
    float kmu = ks1 * (1.f / 32.f), kvar = ks2 * (1.f / 32.f) - kmu * kmu;
    float vmu = vs1 * (1.f / 32.f), vvar = vs2 * (1.f / 32.f) - vmu * vmu;
    float krs = rsqrtf(kvar + LN_EPS), vrs = rsqrtf(vvar + LN_EPS);

    half8_t ky;
    int cs = s_l >> 3, es = s_l & 7;
    #pragma unroll
    for (int j = 0; j < 8; ++j) {
        int d = c * 8 + j;
        float wd = w[d], bd = b[d];
        ky[j] = (f16)((kf[j] - kmu) * krs * wd + bd);
        T[d * 64 + (cs ^ j) * 8 + es] = (f16)((vf[j] - vmu) * vrs * wd + bd);
    }
    *(half8_t*)(Kg + base) = ky;
    __syncthreads();
    int d_o = t >> 3, c_o = t & 7;
    half8_t out = *(const half8_t*)(T + d_o * 64 + c_o * 8);
    *(half8_t*)(Vtg + (size_t)(g * 32 + seg) * 2048 + d_o * 64 + c_o * 8) = out;
}

// ---------------------------------------------------------------- flash attention
// Q-block 128, 4 waves (wave owns 32 q via i=0,1), S-tile 64, dbuf K/V staging,
// bottom-barrier pipeline with explicit vmcnt(0). P: per-wave 32 rows x 128 B,
// XOR-chunk swizzle (bank-uniform writes AND reads). Rowsum via ones-row MFMA.
// grid (16, 64).
__global__ __launch_bounds__(256, 4) void k_flash(
    const f16* __restrict__ Qg, const f16* __restrict__ Kg,
    const f16* __restrict__ Vtg, f16* __restrict__ Og)
{
    __shared__ __align__(16) char smem[32768];
    // Kb[2]: 0/4096 ; Vb[2]: 8192/12288 ; P: 16384 + wid*4096 (Q staged there)

    const int tid = threadIdx.x, wid = tid >> 6, ln = tid & 63;
    const int l15 = ln & 15, quad = ln >> 4, l8 = ln & 7;
    char* Pw = smem + 16384 + wid * 4096;
    const int g = blockIdx.y, h = g & 15, n = g >> 4;
    const int q0 = blockIdx.x * 128;

    // prologue: wave wid stages its chunk c=wid of Q (128 q), K0, V0
    const f16* Qb = Qg + (size_t)g * 65536 + (size_t)wid * 16384 + (size_t)q0 * 8;
    gl_lds16(Qb + (size_t)ln * 8,        smem + 16384 + wid * 2048);
    gl_lds16(Qb + (size_t)(64 + ln) * 8, smem + 16384 + wid * 2048 + 1024);
    const f16* kp = Kg + (size_t)g * 65536 + (size_t)wid * 16384;
    const f16* vp = Vtg + (size_t)(g * 32) * 2048 + wid * 512;
    gl_lds16(kp + (size_t)ln * 8, smem + wid * 1024);
    gl_lds16(vp + (size_t)ln * 8, smem + 8192 + wid * 1024);
    kp += 512;   // next tile
    vp += 2048;
    __builtin_amdgcn_s_waitcnt(0x0F70);   // vmcnt(0)
    __syncthreads();
    half8_t aq[2];
    #pragma unroll
    for (int i = 0; i < 2; ++i)
        aq[i] = *(const half8_t*)(smem + 16384 + quad * 2048 + (wid * 32 + i * 16 + l15) * 16);
    __syncthreads();   // all aq reads done before any P write (race fix)

    // ones A-fragment: row m=0 is all 1 -> MFMA accumulates column sums of B
    half8_t onesf;
    {
        f16 o = (l15 == 0) ? (f16)1.0f : (f16)0.0f;
        #pragma unroll
        for (int j = 0; j < 8; ++j) onesf[j] = o;
    }

    f32x4 z4 = {0.f, 0.f, 0.f, 0.f};
    f32x4 accO[2][2], accSum[2];
    accO[0][0] = z4; accO[0][1] = z4; accO[1][0] = z4; accO[1][1] = z4;
    accSum[0] = z4; accSum[1] = z4;
    float m_i[2] = {-1e30f, -1e30f};

    for (int st = 0; st < 32; ++st) {
        const int cur = st & 1;
        if (st < 31) {
            gl_lds16(kp + (size_t)ln * 8, smem + (cur ^ 1) * 4096 + wid * 1024);
            gl_lds16(vp + (size_t)ln * 8, smem + 8192 + (cur ^ 1) * 4096 + wid * 1024);
            kp += 512;
            vp += 2048;
        }
        const char* Kl = smem + cur * 4096;
        const char* Vt = smem + 8192 + cur * 4096;

        // S^T: A = K (m=s), B = Qscaled (n=q); already in exp2 units
        half8_t ak[4];
        #pragma unroll
        for (int mt = 0; mt < 4; ++mt)
            ak[mt] = *(const half8_t*)(Kl + quad * 1024 + (mt * 16 + l15) * 16);
        f32x4 accS[2][4];
        #pragma unroll
        for (int i = 0; i < 2; ++i)
            #pragma unroll
            for (int mt = 0; mt < 4; ++mt)
                accS[i][mt] = __builtin_amdgcn_mfma_f32_16x16x32_f16(ak[mt], aq[i], z4, 0, 0, 0);

        // per-q max (lane col l15); quad-reduce via shfl
        float mn[2];
        bool up = false;
        #pragma unroll
        for (int i = 0; i < 2; ++i) {
            float xm = fmaxf(fmaxf(accS[i][0][0], accS[i][0][1]),
                             fmaxf(accS[i][0][2], accS[i][0][3]));
            #pragma unroll
            for (int mt = 1; mt < 4; ++mt)
                xm = fmaxf(xm, fmaxf(fmaxf(accS[i][mt][0], accS[i][mt][1]),
                                     fmaxf(accS[i][mt][2], accS[i][mt][3])));
            xm = fmaxf(xm, __shfl_xor(xm, 16));
            xm = fmaxf(xm, __shfl_xor(xm, 32));
            up = up || (xm > m_i[i]);
            mn[i] = fmaxf(m_i[i], xm);
        }
        if (__ballot(up)) {   // wave-uniform: rescale only when some max rose
            #pragma unroll
            for (int i = 0; i < 2; ++i) {
                float alpha = __builtin_amdgcn_exp2f(m_i[i] - mn[i]);
                #pragma unroll
                for (int dt = 0; dt < 2; ++dt)
                    #pragma unroll
                    for (int r = 0; r < 4; ++r) accO[i][dt][r] *= alpha;
                #pragma unroll
                for (int r = 0; r < 4; ++r) accSum[i][r] *= alpha;
            }
        }
        m_i[0] = mn[0]; m_i[1] = mn[1];

        // exp2 + packed P store (swizzled chunks: bank-uniform b64 writes)
        #pragma unroll
        for (int i = 0; i < 2; ++i) {
            #pragma unroll
            for (int mt = 0; mt < 4; ++mt) {
                float p0 = __builtin_amdgcn_exp2f(accS[i][mt][0] - mn[i]);
                float p1 = __builtin_amdgcn_exp2f(accS[i][mt][1] - mn[i]);
                float p2 = __builtin_amdgcn_exp2f(accS[i][mt][2] - mn[i]);
                float p3 = __builtin_amdgcn_exp2f(accS[i][mt][3] - mn[i]);
                int ch = (mt * 2 + (quad >> 1)) ^ l8;
                *(half4_t*)(Pw + (i * 16 + l15) * 128 + ch * 16 + (quad & 1) * 8) =
                    pack4(p0, p1, p2, p3);
            }
        }

        // O^T += V^T·P^T and rowsum += 1^T·P^T (ones-frag MFMA)
        #pragma unroll
        for (int kt = 0; kt < 2; ++kt) {
            half8_t av[2], bp[2];
            #pragma unroll
            for (int dt = 0; dt < 2; ++dt) {
                int d = dt * 16 + l15;
                int cp = (kt * 4 + quad) ^ (l15 & 7);
                av[dt] = *(const half8_t*)(Vt + d * 128 + cp * 16);
            }
            #pragma unroll
            for (int i = 0; i < 2; ++i)
                bp[i] = *(const half8_t*)(Pw + (i * 16 + l15) * 128 +
                                          (((kt * 4 + quad) ^ l8) * 16));
            #pragma unroll
            for (int i = 0; i < 2; ++i) {
                #pragma unroll
                for (int dt = 0; dt < 2; ++dt)
                    accO[i][dt] = __builtin_amdgcn_mfma_f32_16x16x32_f16(av[dt], bp[i], accO[i][dt], 0, 0, 0);
                accSum[i] = __builtin_amdgcn_mfma_f32_16x16x32_f16(onesf, bp[i], accSum[i], 0, 0, 0);
            }
        }

        __builtin_amdgcn_s_waitcnt(0x0F70);   // drain prefetch DMA (R4 race fix)
        __syncthreads();
    }

    // epilogue: l_i lives in accSum[i][0] on quad-0 lanes (C row 0); broadcast.
    // normalize, transpose via wave-private LDS (32 rows x 80 B), coalesced store.
    #pragma unroll
    for (int i = 0; i < 2; ++i) {
        float li = __shfl(accSum[i][0], l15);
        float inv = 1.f / li;
        #pragma unroll
        for (int dt = 0; dt < 2; ++dt)
            *(half4_t*)(Pw + (i * 16 + l15) * 80 + (dt * 16 + quad * 4) * 2) =
                pack4(accO[i][dt][0] * inv, accO[i][dt][1] * inv,
                      accO[i][dt][2] * inv, accO[i][dt][3] * inv);
    }
    int q2 = ln >> 1, hf = ln & 1;
    half8_t o0 = *(const half8_t*)(Pw + q2 * 80 + hf * 32);
    half8_t o1 = *(const half8_t*)(Pw + q2 * 80 + hf * 32 + 16);
    size_t rowe = ((size_t)(n * 2048 + q0 + wid * 32 + q2)) * 512 + h * 32 + hf * 16;
    *(half8_t*)(Og + rowe) = o0;
    *(half8_t*)(Og + rowe + 8) = o1;
}

// ---------------------------------------------------------------- out-projection
// Out = O @ W2^T + b ; O f16 [n][l][512] (rows m = n*2048+l), Out f32 rows l*4+n.
__global__ __launch_bounds__(256) void k_outproj(
    const f16* __restrict__ A, const f16* __restrict__ W2,
    const float* __restrict__ bias, float* __restrict__ Out)
{
    __shared__ __align__(16) f16 Al[128 * 32];
    __shared__ __align__(16) f16 Bl[128 * 32];

    const int tid = threadIdx.x;
    const int m0 = blockIdx.x * 128;
    const int f0 = blockIdx.y * 128;
    const int wid = tid >> 6, ln = tid & 63, l15 = ln & 15, quad = ln >> 4;
    const int wm = wid >> 1, wn = wid & 1;

    f32x4 z4 = {0.f, 0.f, 0.f, 0.f};
    f32x4 acc[4][4];
    #pragma unroll
    for (int i = 0; i < 4; ++i)
        #pragma unroll
        for (int j = 0; j < 4; ++j) acc[i][j] = z4;

    for (int kt = 0; kt < 16; ++kt) {
        const int k0 = kt * 32;
        #pragma unroll
        for (int i = 0; i < 2; ++i) {
            int row = wid * 32 + i * 16 + (ln >> 2);
            gl_lds16(A + (size_t)(m0 + row) * 512 + k0 + (ln & 3) * 8,
                     Al + (wid * 32 + i * 16) * 32);
            gl_lds16(W2 + (size_t)(f0 + row) * 512 + k0 + (ln & 3) * 8,
                     Bl + (wid * 32 + i * 16) * 32);
        }
        __syncthreads();

        half8_t a[4], b[4];
        #pragma unroll
        for (int i = 0; i < 4; ++i)
            a[i] = *(const half8_t*)(Al + (wm * 64 + i * 16 + l15) * 32 + quad * 8);
        #pragma unroll
        for (int j = 0; j < 4; ++j)
            b[j] = *(const half8_t*)(Bl + (wn * 64 + j * 16 + l15) * 32 + quad * 8);
        #pragma unroll
        for (int i = 0; i < 4; ++i)
            #pragma unroll
            for (int j = 0; j < 4; ++j)
                acc[i][j] = __builtin_amdgcn_mfma_f32_16x16x32_f16(b[j], a[i], acc[i][j], 0, 0, 0);
        __syncthreads();
    }

    #pragma unroll
    for (int j = 0; j < 4; ++j) {
        int fb = f0 + wn * 64 + j * 16;
        float4 bs4 = *(const float4*)(bias + fb + quad * 4);
        #pragma unroll
        for (int i = 0; i < 4; ++i) {
            int rm = m0 + wm * 64 + i * 16 + l15;
            int orow = (rm & 2047) * 4 + (rm >> 11);
            float4 o;
            o.x = acc[i][j][0] + bs4.x;
            o.y = acc[i][j][1] + bs4.y;
            o.z = acc[i][j][2] + bs4.z;
            o.w = acc[i][j][3] + bs4.w;
            *(float4*)(Out + (size_t)orow * 512 + fb + quad * 4) = o;
        }
    }
}

// ---------------------------------------------------------------- launch
extern "C" void kernel_launch(void* const* d_in, const int* in_sizes, int n_in,
                              void* d_out, int out_size, void* d_ws, size_t ws_size,
                              hipStream_t stream) {
    const float* query   = (const float*)d_in[0];
    const float* key_in  = (const float*)d_in[1];
    const float* value   = (const float*)d_in[2];
    const float* scaling = (const float*)d_in[3];
    const float* ipw     = (const float*)d_in[4];
    const float* ipb     = (const float*)d_in[5];
    const float* pnw     = (const float*)d_in[6];
    const float* pnb     = (const float*)d_in[7];
    const float* opw     = (const float*)d_in[8];
    const float* opb     = (const float*)d_in[9];
    float* out = (float*)d_out;

    // workspace (f16 elements): Qg,Kg,Vg,Vtg each 4,194,304; W1 786,432; W2 262,144
    // Og aliases Vg (Vg fully consumed by k_norm_kv before k_flash writes Og).
    f16* Qg  = (f16*)d_ws;
    f16* Kg  = Qg  + (size_t)4194304;
    f16* Vg  = Kg  + (size_t)4194304;
    f16* Vtg = Vg  + (size_t)4194304;
    f16* W1  = Vtg + (size_t)4194304;
    f16* W2  = W1  + (size_t)786432;
    f16* Og  = Vg;   // alias
    // total: 35,651,584 bytes

    k_cast<<<1024, 256, 0, stream>>>(ipw, opw, W1, W2);
    k_inproj<<<dim3(64, 12), 256, 0, stream>>>(query, key_in, value, W1, ipb, scaling, Qg, Kg, Vg);
    k_norm_kv<<<dim3(32, 64), 256, 0, stream>>>(Kg, Vg, pnw, pnb, Vtg);
    k_flash<<<dim3(16, 64), 256, 0, stream>>>(Qg, Kg, Vtg, Og);
    k_outproj<<<dim3(64, 4), 256, 0, stream>>>(Og, W2, opb, out);
}

// Round 8
// 220.250 us; speedup vs baseline: 1.1148x; 1.0488x over previous
//
#include <hip/hip_runtime.h>
#include <cstdint>

// Problem constants
#define LN_EPS 1e-5f

typedef _Float16 f16;
typedef _Float16 half4_t __attribute__((ext_vector_type(4)));
typedef _Float16 half8_t __attribute__((ext_vector_type(8)));
typedef __fp16 fp16v2 __attribute__((ext_vector_type(2)));
typedef float f32x4 __attribute__((ext_vector_type(4)));

// async global->LDS, 16B per lane; LDS dest = wave-uniform base + lane*16
__device__ __forceinline__ void gl_lds16(const void* g, void* l) {
    __builtin_amdgcn_global_load_lds(
        (__attribute__((address_space(1))) void*)(uintptr_t)g,
        (__attribute__((address_space(3))) void*)(uint32_t)(uintptr_t)l,
        16, 0, 0);
}

// pack 4 floats -> 4 f16 via v_cvt_pkrtz
__device__ __forceinline__ half4_t pack4(float a, float b, float c, float d) {
    fp16v2 lo = __builtin_amdgcn_cvt_pkrtz(a, b);
    fp16v2 hi = __builtin_amdgcn_cvt_pkrtz(c, d);
    half4_t r;
    r[0] = (f16)lo[0]; r[1] = (f16)lo[1]; r[2] = (f16)hi[0]; r[3] = (f16)hi[1];
    return r;
}

// ---------------------------------------------------------------- cast weights + inputs
// W1 (1536x512), W2 (512x512), and X = [query|key_in|value] (3 x 8192x512) -> f16.
__global__ void k_cast(const float* __restrict__ W1f, const float* __restrict__ W2f,
                       const float* __restrict__ Xq, const float* __restrict__ Xk,
                       const float* __restrict__ Xv,
                       f16* __restrict__ W1h, f16* __restrict__ W2h,
                       f16* __restrict__ Xh) {
    int t = blockIdx.x * blockDim.x + threadIdx.x;   // 13312*256 = 3,407,872 float4
    const float4* src;
    half4_t* dst;
    int idx;
    if (t < 196608)      { src = (const float4*)W1f; dst = (half4_t*)W1h; idx = t; }
    else if (t < 262144) { src = (const float4*)W2f; dst = (half4_t*)W2h; idx = t - 196608; }
    else {
        int u = t - 262144;               // 0 .. 3,145,727
        int s = u >> 20;                  // input selector (2^20 float4 per input)
        idx = u & 1048575;
        src = (s == 0) ? (const float4*)Xq : ((s == 1) ? (const float4*)Xk : (const float4*)Xv);
        dst = (half4_t*)(Xh + (size_t)s * 4194304);
    }
    float4 v = src[idx];
    dst[idx] = pack4(v.x, v.y, v.z, v.w);
}

// ---------------------------------------------------------------- in-projection
// C = X @ W^T + b ; X f16 (per-section 8192x512), W f16. Pure m97-pattern K-loop:
// both A and B staged via gl_lds16. Outputs chunk-major per-(n,h): T[g][c][len][8].
// Q pre-scaled by beta*log2(e).
__global__ __launch_bounds__(256) void k_inproj(
    const f16* __restrict__ Xh, const f16* __restrict__ W1,
    const float* __restrict__ bias, const float* __restrict__ scaling,
    f16* __restrict__ Qg, f16* __restrict__ Kg, f16* __restrict__ Vg)
{
    __shared__ __align__(16) f16 Al[128 * 32];
    __shared__ __align__(16) f16 Bl[128 * 32];

    const int tid = threadIdx.x;
    const int m0 = blockIdx.x * 128;
    const int f0 = blockIdx.y * 128;          // global output-feature base [0,1536)
    const int sec = f0 >> 9;
    const f16* X = Xh + (size_t)sec * 4194304;
    f16* Ob = (sec == 0) ? Qg : ((sec == 1) ? Kg : Vg);

    const int wid = tid >> 6, ln = tid & 63, l15 = ln & 15, quad = ln >> 4;
    const int wm = wid >> 1, wn = wid & 1;

    f32x4 z4 = {0.f, 0.f, 0.f, 0.f};
    f32x4 acc[4][4];
    #pragma unroll
    for (int i = 0; i < 4; ++i)
        #pragma unroll
        for (int j = 0; j < 4; ++j) acc[i][j] = z4;

    for (int kt = 0; kt < 16; ++kt) {
        const int k0 = kt * 32;
        #pragma unroll
        for (int i = 0; i < 2; ++i) {
            int row = wid * 32 + i * 16 + (ln >> 2);
            int co = (ln & 3) * 8;
            gl_lds16(W1 + (size_t)(f0 + row) * 512 + k0 + co,
                     Bl + (wid * 32 + i * 16) * 32);
            gl_lds16(X + (size_t)(m0 + row) * 512 + k0 + co,
                     Al + (wid * 32 + i * 16) * 32);
        }
        __syncthreads();

        half8_t a[4], b[4];
        #pragma unroll
        for (int i = 0; i < 4; ++i)
            a[i] = *(const half8_t*)(Al + (wm * 64 + i * 16 + l15) * 32 + quad * 8);
        #pragma unroll
        for (int j = 0; j < 4; ++j)
            b[j] = *(const half8_t*)(Bl + (wn * 64 + j * 16 + l15) * 32 + quad * 8);
        #pragma unroll
        for (int i = 0; i < 4; ++i)
            #pragma unroll
            for (int j = 0; j < 4; ++j)
                acc[i][j] = __builtin_amdgcn_mfma_f32_16x16x32_f16(b[j], a[i], acc[i][j], 0, 0, 0);
        __syncthreads();
    }

    // epilogue: C cols (l15) = X row, C rows (quad*4+r) = feature.
    #pragma unroll
    for (int j = 0; j < 4; ++j) {
        int fb = f0 + wn * 64 + j * 16;       // feature base of this 16-tile
        int floc = (fb & 511) + quad * 4;     // per-lane feature within section
        int hh = floc >> 5;
        int cc = (floc >> 3) & 3, e0 = floc & 7;
        float sc2 = (sec == 0) ? scaling[hh] * 1.44269504f : 1.0f;
        float4 bs4 = *(const float4*)(bias + fb + quad * 4);
        #pragma unroll
        for (int i = 0; i < 4; ++i) {
            int rm = m0 + wm * 64 + i * 16 + l15;
            int l = rm >> 2, nb = rm & 3;
            int gg = nb * 16 + hh;
            *(half4_t*)(Ob + (size_t)gg * 65536 + (size_t)cc * 16384 + (size_t)l * 8 + e0) =
                pack4((acc[i][j][0] + bs4.x) * sc2, (acc[i][j][1] + bs4.y) * sc2,
                      (acc[i][j][2] + bs4.z) * sc2, (acc[i][j][3] + bs4.w) * sc2);
        }
    }
}

// ---------------------------------------------------------------- LayerNorm K (in place) + V (normed, transposed)
// grid (32, 64): seg=64 s-rows, g. thread (s_l = t>>2, c = t&3) per matrix.
// Vg [g][c][2048][8] -> Vtg [g][seg][d=32][c'=8][8], c' = c_s XOR (d&7)
__global__ void k_norm_kv(f16* __restrict__ Kg, const f16* __restrict__ Vg,
                          const float* __restrict__ w, const float* __restrict__ b,
                          f16* __restrict__ Vtg) {
    __shared__ __align__(16) f16 T[32 * 64];   // [d][c'][8]
    const int t = threadIdx.x;
    const int seg = blockIdx.x, g = blockIdx.y;
    const int s_l = t >> 2, c = t & 3;
    const size_t base = (size_t)g * 65536 + (size_t)c * 16384 + (size_t)(seg * 64 + s_l) * 8;

    half8_t kv = *(const half8_t*)(Kg + base);
    half8_t vv = *(const half8_t*)(Vg + base);
    float kf[8], vf[8];
    float ks1 = 0.f, ks2 = 0.f, vs1 = 0.f, vs2 = 0.f;
    #pragma unroll
    for (int j = 0; j < 8; ++j) {
        kf[j] = (float)kv[j]; ks1 += kf[j]; ks2 += kf[j] * kf[j];
        vf[j] = (float)vv[j]; vs1 += vf[j]; vs2 += vf[j] * vf[j];
    }
    ks1 += __shfl_xor(ks1, 1); ks1 += __shfl_xor(ks1, 2);
    ks2 += __shfl_xor(ks2, 1); ks2 += __shfl_xor(ks2, 2);
    vs1 += __shfl_xor(vs1, 1); vs1 += __shfl_xor(vs1, 2);
    vs2 += __shfl_xor(vs2, 1); vs2 += __shfl_xor(vs2, 2);
    float kmu = ks1 * (1.f / 32.f), kvar = ks2 * (1.f / 32.f) - kmu * kmu;
    float vmu = vs1 * (1.f / 32.f), vvar = vs2 * (1.f / 32.f) - vmu * vmu;
    float krs = rsqrtf(kvar + LN_EPS), vrs = rsqrtf(vvar + LN_EPS);

    half8_t ky;
    int cs = s_l >> 3, es = s_l & 7;
    #pragma unroll
    for (int j = 0; j < 8; ++j) {
        int d = c * 8 + j;
        float wd = w[d], bd = b[d];
        ky[j] = (f16)((kf[j] - kmu) * krs * wd + bd);
        T[d * 64 + (cs ^ j) * 8 + es] = (f16)((vf[j] - vmu) * vrs * wd + bd);
    }
    *(half8_t*)(Kg + base) = ky;
    __syncthreads();
    int d_o = t >> 3, c_o = t & 7;
    half8_t out = *(const half8_t*)(T + d_o * 64 + c_o * 8);
    *(half8_t*)(Vtg + (size_t)(g * 32 + seg) * 2048 + d_o * 64 + c_o * 8) = out;
}

// ---------------------------------------------------------------- flash attention
// R6-proven online-softmax kernel; grid transposed to (g, q-block) so the 16
// q-blocks of one g land on one XCD (%8 heuristic) -> K/V L2-resident.
// Q-block 128, 4 waves, S-tile 64, dbuf staging, bottom-barrier + explicit vmcnt(0).
__global__ __launch_bounds__(256, 4) void k_flash(
    const f16* __restrict__ Qg, const f16* __restrict__ Kg,
    const f16* __restrict__ Vtg, f16* __restrict__ Og)
{
    __shared__ __align__(16) char smem[32768];
    // Kb[2]: 0/4096 ; Vb[2]: 8192/12288 ; P: 16384 + wid*4096 (Q staged there)

    const int tid = threadIdx.x, wid = tid >> 6, ln = tid & 63;
    const int l15 = ln & 15, quad = ln >> 4, l8 = ln & 7;
    char* Pw = smem + 16384 + wid * 4096;
    const int g = blockIdx.x, h = g & 15, n = g >> 4;
    const int q0 = blockIdx.y * 128;

    // prologue: wave wid stages its chunk c=wid of Q (128 q), K0, V0
    const f16* Qb = Qg + (size_t)g * 65536 + (size_t)wid * 16384 + (size_t)q0 * 8;
    gl_lds16(Qb + (size_t)ln * 8,        smem + 16384 + wid * 2048);
    gl_lds16(Qb + (size_t)(64 + ln) * 8, smem + 16384 + wid * 2048 + 1024);
    const f16* kp = Kg + (size_t)g * 65536 + (size_t)wid * 16384;
    const f16* vp = Vtg + (size_t)(g * 32) * 2048 + wid * 512;
    gl_lds16(kp + (size_t)ln * 8, smem + wid * 1024);
    gl_lds16(vp + (size_t)ln * 8, smem + 8192 + wid * 1024);
    kp += 512;   // next tile
    vp += 2048;
    __builtin_amdgcn_s_waitcnt(0x0F70);   // vmcnt(0)
    __syncthreads();
    half8_t aq[2];
    #pragma unroll
    for (int i = 0; i < 2; ++i)
        aq[i] = *(const half8_t*)(smem + 16384 + quad * 2048 + (wid * 32 + i * 16 + l15) * 16);
    __syncthreads();   // all aq reads done before any P write (race fix)

    // ones A-fragment: row m=0 is all 1 -> MFMA accumulates column sums of B
    half8_t onesf;
    {
        f16 o = (l15 == 0) ? (f16)1.0f : (f16)0.0f;
        #pragma unroll
        for (int j = 0; j < 8; ++j) onesf[j] = o;
    }

    f32x4 z4 = {0.f, 0.f, 0.f, 0.f};
    f32x4 accO[2][2], accSum[2];
    accO[0][0] = z4; accO[0][1] = z4; accO[1][0] = z4; accO[1][1] = z4;
    accSum[0] = z4; accSum[1] = z4;
    float m_i[2] = {-1e30f, -1e30f};

    for (int st = 0; st < 32; ++st) {
        const int cur = st & 1;
        if (st < 31) {
            gl_lds16(kp + (size_t)ln * 8, smem + (cur ^ 1) * 4096 + wid * 1024);
            gl_lds16(vp + (size_t)ln * 8, smem + 8192 + (cur ^ 1) * 4096 + wid * 1024);
            kp += 512;
            vp += 2048;
        }
        const char* Kl = smem + cur * 4096;
        const char* Vt = smem + 8192 + cur * 4096;

        // S^T: A = K (m=s), B = Qscaled (n=q); already in exp2 units
        half8_t ak[4];
        #pragma unroll
        for (int mt = 0; mt < 4; ++mt)
            ak[mt] = *(const half8_t*)(Kl + quad * 1024 + (mt * 16 + l15) * 16);
        f32x4 accS[2][4];
        #pragma unroll
        for (int i = 0; i < 2; ++i)
            #pragma unroll
            for (int mt = 0; mt < 4; ++mt)
                accS[i][mt] = __builtin_amdgcn_mfma_f32_16x16x32_f16(ak[mt], aq[i], z4, 0, 0, 0);

        // per-q max (lane col l15); quad-reduce via shfl
        float mn[2];
        bool up = false;
        #pragma unroll
        for (int i = 0; i < 2; ++i) {
            float xm = fmaxf(fmaxf(accS[i][0][0], accS[i][0][1]),
                             fmaxf(accS[i][0][2], accS[i][0][3]));
            #pragma unroll
            for (int mt = 1; mt < 4; ++mt)
                xm = fmaxf(xm, fmaxf(fmaxf(accS[i][mt][0], accS[i][mt][1]),
                                     fmaxf(accS[i][mt][2], accS[i][mt][3])));
            xm = fmaxf(xm, __shfl_xor(xm, 16));
            xm = fmaxf(xm, __shfl_xor(xm, 32));
            up = up || (xm > m_i[i]);
            mn[i] = fmaxf(m_i[i], xm);
        }
        if (__ballot(up)) {   // wave-uniform: rescale only when some max rose
            #pragma unroll
            for (int i = 0; i < 2; ++i) {
                float alpha = __builtin_amdgcn_exp2f(m_i[i] - mn[i]);
                #pragma unroll
                for (int dt = 0; dt < 2; ++dt)
                    #pragma unroll
                    for (int r = 0; r < 4; ++r) accO[i][dt][r] *= alpha;
                #pragma unroll
                for (int r = 0; r < 4; ++r) accSum[i][r] *= alpha;
            }
        }
        m_i[0] = mn[0]; m_i[1] = mn[1];

        // exp2 + packed P store (swizzled chunks: bank-uniform b64 writes)
        #pragma unroll
        for (int i = 0; i < 2; ++i) {
            #pragma unroll
            for (int mt = 0; mt < 4; ++mt) {
                float p0 = __builtin_amdgcn_exp2f(accS[i][mt][0] - mn[i]);
                float p1 = __builtin_amdgcn_exp2f(accS[i][mt][1] - mn[i]);
                float p2 = __builtin_amdgcn_exp2f(accS[i][mt][2] - mn[i]);
                float p3 = __builtin_amdgcn_exp2f(accS[i][mt][3] - mn[i]);
                int ch = (mt * 2 + (quad >> 1)) ^ l8;
                *(half4_t*)(Pw + (i * 16 + l15) * 128 + ch * 16 + (quad & 1) * 8) =
                    pack4(p0, p1, p2, p3);
            }
        }

        // O^T += V^T·P^T and rowsum += 1^T·P^T (ones-frag MFMA)
        #pragma unroll
        for (int kt = 0; kt < 2; ++kt) {
            half8_t av[2], bp[2];
            #pragma unroll
            for (int dt = 0; dt < 2; ++dt) {
                int d = dt * 16 + l15;
                int cp = (kt * 4 + quad) ^ (l15 & 7);
                av[dt] = *(const half8_t*)(Vt + d * 128 + cp * 16);
            }
            #pragma unroll
            for (int i = 0; i < 2; ++i)
                bp[i] = *(const half8_t*)(Pw + (i * 16 + l15) * 128 +
                                          (((kt * 4 + quad) ^ l8) * 16));
            #pragma unroll
            for (int i = 0; i < 2; ++i) {
                #pragma unroll
                for (int dt = 0; dt < 2; ++dt)
                    accO[i][dt] = __builtin_amdgcn_mfma_f32_16x16x32_f16(av[dt], bp[i], accO[i][dt], 0, 0, 0);
                accSum[i] = __builtin_amdgcn_mfma_f32_16x16x32_f16(onesf, bp[i], accSum[i], 0, 0, 0);
            }
        }

        __builtin_amdgcn_s_waitcnt(0x0F70);   // drain prefetch DMA (R4 race fix)
        __syncthreads();
    }

    // epilogue: l_i lives in accSum[i][0] on quad-0 lanes (C row 0); broadcast.
    // normalize, transpose via wave-private LDS (32 rows x 80 B), coalesced store.
    #pragma unroll
    for (int i = 0; i < 2; ++i) {
        float li = __shfl(accSum[i][0], l15);
        float inv = 1.f / li;
        #pragma unroll
        for (int dt = 0; dt < 2; ++dt)
            *(half4_t*)(Pw + (i * 16 + l15) * 80 + (dt * 16 + quad * 4) * 2) =
                pack4(accO[i][dt][0] * inv, accO[i][dt][1] * inv,
                      accO[i][dt][2] * inv, accO[i][dt][3] * inv);
    }
    int q2 = ln >> 1, hf = ln & 1;
    half8_t o0 = *(const half8_t*)(Pw + q2 * 80 + hf * 32);
    half8_t o1 = *(const half8_t*)(Pw + q2 * 80 + hf * 32 + 16);
    size_t rowe = ((size_t)(n * 2048 + q0 + wid * 32 + q2)) * 512 + h * 32 + hf * 16;
    *(half8_t*)(Og + rowe) = o0;
    *(half8_t*)(Og + rowe + 8) = o1;
}

// ---------------------------------------------------------------- out-projection
// Out = O @ W2^T + b ; O f16 [n][l][512] (rows m = n*2048+l), Out f32 rows l*4+n.
__global__ __launch_bounds__(256) void k_outproj(
    const f16* __restrict__ A, const f16* __restrict__ W2,
    const float* __restrict__ bias, float* __restrict__ Out)
{
    __shared__ __align__(16) f16 Al[128 * 32];
    __shared__ __align__(16) f16 Bl[128 * 32];

    const int tid = threadIdx.x;
    const int m0 = blockIdx.x * 128;
    const int f0 = blockIdx.y * 128;
    const int wid = tid >> 6, ln = tid & 63, l15 = ln & 15, quad = ln >> 4;
    const int wm = wid >> 1, wn = wid & 1;

    f32x4 z4 = {0.f, 0.f, 0.f, 0.f};
    f32x4 acc[4][4];
    #pragma unroll
    for (int i = 0; i < 4; ++i)
        #pragma unroll
        for (int j = 0; j < 4; ++j) acc[i][j] = z4;

    for (int kt = 0; kt < 16; ++kt) {
        const int k0 = kt * 32;
        #pragma unroll
        for (int i = 0; i < 2; ++i) {
            int row = wid * 32 + i * 16 + (ln >> 2);
            gl_lds16(A + (size_t)(m0 + row) * 512 + k0 + (ln & 3) * 8,
                     Al + (wid * 32 + i * 16) * 32);
            gl_lds16(W2 + (size_t)(f0 + row) * 512 + k0 + (ln & 3) * 8,
                     Bl + (wid * 32 + i * 16) * 32);
        }
        __syncthreads();

        half8_t a[4], b[4];
        #pragma unroll
        for (int i = 0; i < 4; ++i)
            a[i] = *(const half8_t*)(Al + (wm * 64 + i * 16 + l15) * 32 + quad * 8);
        #pragma unroll
        for (int j = 0; j < 4; ++j)
            b[j] = *(const half8_t*)(Bl + (wn * 64 + j * 16 + l15) * 32 + quad * 8);
        #pragma unroll
        for (int i = 0; i < 4; ++i)
            #pragma unroll
            for (int j = 0; j < 4; ++j)
                acc[i][j] = __builtin_amdgcn_mfma_f32_16x16x32_f16(b[j], a[i], acc[i][j], 0, 0, 0);
        __syncthreads();
    }

    #pragma unroll
    for (int j = 0; j < 4; ++j) {
        int fb = f0 + wn * 64 + j * 16;
        float4 bs4 = *(const float4*)(bias + fb + quad * 4);
        #pragma unroll
        for (int i = 0; i < 4; ++i) {
            int rm = m0 + wm * 64 + i * 16 + l15;
            int orow = (rm & 2047) * 4 + (rm >> 11);
            float4 o;
            o.x = acc[i][j][0] + bs4.x;
            o.y = acc[i][j][1] + bs4.y;
            o.z = acc[i][j][2] + bs4.z;
            o.w = acc[i][j][3] + bs4.w;
            *(float4*)(Out + (size_t)orow * 512 + fb + quad * 4) = o;
        }
    }
}

// ---------------------------------------------------------------- launch
extern "C" void kernel_launch(void* const* d_in, const int* in_sizes, int n_in,
                              void* d_out, int out_size, void* d_ws, size_t ws_size,
                              hipStream_t stream) {
    const float* query   = (const float*)d_in[0];
    const float* key_in  = (const float*)d_in[1];
    const float* value   = (const float*)d_in[2];
    const float* scaling = (const float*)d_in[3];
    const float* ipw     = (const float*)d_in[4];
    const float* ipb     = (const float*)d_in[5];
    const float* pnw     = (const float*)d_in[6];
    const float* pnb     = (const float*)d_in[7];
    const float* opw     = (const float*)d_in[8];
    const float* opb     = (const float*)d_in[9];
    float* out = (float*)d_out;

    // workspace (f16 element offsets):
    //   Qg 0 / Kg 4,194,304 / Vg 8,388,608 (each 4,194,304)
    //   W1 12,582,912 (786,432) / W2 13,369,344 (262,144)
    //   Xh 13,631,488 (12,582,912; dead after k_inproj)
    //   Vtg aliases Xh head (4,194,304); Og aliases Vg (dead after k_norm_kv)
    // total: 52,428,800 bytes
    f16* Qg  = (f16*)d_ws;
    f16* Kg  = Qg + (size_t)4194304;
    f16* Vg  = Qg + (size_t)8388608;
    f16* W1  = Qg + (size_t)12582912;
    f16* W2  = Qg + (size_t)13369344;
    f16* Xh  = Qg + (size_t)13631488;
    f16* Vtg = Xh;   // alias (Xh consumed before k_norm_kv writes Vtg)
    f16* Og  = Vg;   // alias

    k_cast<<<13312, 256, 0, stream>>>(ipw, opw, query, key_in, value, W1, W2, Xh);
    k_inproj<<<dim3(64, 12), 256, 0, stream>>>(Xh, W1, ipb, scaling, Qg, Kg, Vg);
    k_norm_kv<<<dim3(32, 64), 256, 0, stream>>>(Kg, Vg, pnw, pnb, Vtg);
    k_flash<<<dim3(64, 16), 256, 0, stream>>>(Qg, Kg, Vtg, Og);
    k_outproj<<<dim3(64, 4), 256, 0, stream>>>(Og, W2, opb, out);
}